// Round 6
// baseline (288.798 us; speedup 1.0000x reference)
//
#include <hip/hip_runtime.h>

typedef __bf16 bf16;
typedef __attribute__((ext_vector_type(8))) __bf16 bf16x8;
typedef __attribute__((ext_vector_type(2))) __bf16 bf16x2;
typedef __attribute__((ext_vector_type(4))) float f32x4;
typedef __attribute__((ext_vector_type(16))) float f32x16;
typedef __attribute__((ext_vector_type(8))) unsigned short ushort8;   // 16B
typedef __attribute__((ext_vector_type(4))) unsigned short ushort4v;  // 8B

__device__ __forceinline__ unsigned short f2bf(float f) {
    union { float f; unsigned int u; } v; v.f = f;
    unsigned int u = v.u;
    return (unsigned short)((u + 0x7fffu + ((u >> 16) & 1u)) >> 16);
}

#if __has_builtin(__builtin_amdgcn_cvt_pk_bf16_f32)
__device__ __forceinline__ unsigned int pk2bf(float a, float b) {
    union { bf16x2 v; unsigned int u; } c;
    c.v = __builtin_amdgcn_cvt_pk_bf16_f32(a, b);
    return c.u;
}
#else
__device__ __forceinline__ unsigned int pk2bf(float a, float b) {
    return (unsigned int)f2bf(a) | ((unsigned int)f2bf(b) << 16);
}
#endif

__device__ __forceinline__ f32x4 mfma16(bf16x8 a, bf16x8 b, f32x4 c) {
    return __builtin_amdgcn_mfma_f32_16x16x32_bf16(a, b, c, 0, 0, 0);
}
__device__ __forceinline__ f32x16 mfma32(bf16x8 a, bf16x8 b, f32x16 c) {
    return __builtin_amdgcn_mfma_f32_32x32x16_bf16(a, b, c, 0, 0, 0);
}

// async global->LDS 16B: HW places lane i's data at ldsbase + i*16 (wave-uniform base).
#if __has_builtin(__builtin_amdgcn_global_load_lds)
__device__ __forceinline__ void gload16(const unsigned short* g, unsigned short* l) {
    typedef const unsigned int __attribute__((address_space(1)))* gp_t;
    typedef unsigned int __attribute__((address_space(3)))* lp_t;
    __builtin_amdgcn_global_load_lds((gp_t)(const void*)g, (lp_t)(void*)l, 16, 0, 0);
}
#define GLL_LANE 1
#else
#define GLL_LANE 0
#endif

// ---------------- fused fp32 -> bf16 convert ----------------
__global__ void cvt3_f32_bf16(const float* __restrict__ x, const float* __restrict__ wq,
                              const float* __restrict__ wp,
                              unsigned short* __restrict__ xb, unsigned short* __restrict__ wqb,
                              unsigned short* __restrict__ wpb) {
    int i = blockIdx.x * 256 + threadIdx.x;   // float4 index
    const float* in; unsigned short* out; int base;
    if (i < 1572864)      { in = x;  out = xb;  base = i; }
    else if (i < 2015232) { in = wq; out = wqb; base = i - 1572864; }
    else if (i < 2162688) { in = wp; out = wpb; base = i - 2015232; }
    else return;
    float4 f = reinterpret_cast<const float4*>(in)[base];
    union { ushort4v v; unsigned int u[2]; } o;
    o.u[0] = pk2bf(f.x, f.y);
    o.u[1] = pk2bf(f.z, f.w);
    reinterpret_cast<ushort4v*>(out)[base] = o.v;
}

// key permutation for 32x32 S^T C-layout -> PV A-layout:  p: a -> bits (a0,a1,a3,a4,a2)
__device__ __forceinline__ int kperm(int k5) {
    return (k5 & 3) | (((k5 >> 3) & 1) << 2) | (((k5 >> 4) & 1) << 3) | (((k5 >> 2) & 1) << 4);
}
__device__ __forceinline__ int kperm_inv(int p5) {
    return (p5 & 3) | (((p5 >> 4) & 1) << 2) | (((p5 >> 2) & 1) << 3) | (((p5 >> 3) & 1) << 4);
}

// ---------------- QKV GEMM -> fragment-ready chunked layouts ----------------
__global__ __launch_bounds__(256) void qkv_gemm(const unsigned short* __restrict__ A,
                                                const unsigned short* __restrict__ W,
                                                unsigned short* __restrict__ Qf,
                                                unsigned short* __restrict__ Kf,
                                                unsigned short* __restrict__ Vf) {
    __shared__ __align__(16) char smem[34816];
    unsigned short* As = (unsigned short*)smem;            // 128x32 (8 KB)
    unsigned short* Bs = (unsigned short*)(smem + 8192);   // 128x32 (8 KB)
    unsigned short* T  = (unsigned short*)smem;            // epilogue tile 128x136 (34816 B)
    const int t = threadIdx.x;
    const int w = t >> 6, l = t & 63;
    const int wm = (w >> 1) * 64, wn = (w & 1) * 64;
    const int lr = l & 15, lq = l >> 4;
    const int m0 = blockIdx.y * 128, n0 = blockIdx.x * 128;
    f32x4 acc[4][4] = {};
    for (int k0 = 0; k0 < 768; k0 += 32) {
        __syncthreads();
#pragma unroll
        for (int i = 0; i < 2; ++i) {
            int v = t + i * 256;
            int r = v >> 2, c8 = (v & 3) * 8;
#if GLL_LANE
            gload16(&A[(m0 + r) * 768 + k0 + c8], &As[(w * 64 + i * 256) * 8]);
            gload16(&W[(n0 + r) * 768 + k0 + c8], &Bs[(w * 64 + i * 256) * 8]);
#else
            *reinterpret_cast<ushort8*>(&As[r * 32 + c8]) =
                *reinterpret_cast<const ushort8*>(&A[(m0 + r) * 768 + k0 + c8]);
            *reinterpret_cast<ushort8*>(&Bs[r * 32 + c8]) =
                *reinterpret_cast<const ushort8*>(&W[(n0 + r) * 768 + k0 + c8]);
#endif
        }
        __syncthreads();   // compiler drains vmcnt(0) before s_barrier -> LDS data visible
        bf16x8 af[4], bfr[4];
#pragma unroll
        for (int mt = 0; mt < 4; ++mt)
            af[mt] = *reinterpret_cast<const bf16x8*>(&As[(wm + mt * 16 + lr) * 32 + lq * 8]);
#pragma unroll
        for (int nt = 0; nt < 4; ++nt)
            bfr[nt] = *reinterpret_cast<const bf16x8*>(&Bs[(wn + nt * 16 + lr) * 32 + lq * 8]);
#pragma unroll
        for (int mt = 0; mt < 4; ++mt)
#pragma unroll
            for (int nt = 0; nt < 4; ++nt)
                acc[mt][nt] = mfma16(af[mt], bfr[nt], acc[mt][nt]);
    }
    // ---- epilogue: C tile -> LDS (V region transposed) -> coalesced b128 stores ----
    const int tsel = n0 / 768;   // whole block is one of Q/K/V
    __syncthreads();             // As/Bs fragment reads done; reuse as T
    if (tsel < 2) {
#pragma unroll
        for (int nt = 0; nt < 4; ++nt)
#pragma unroll
            for (int mt = 0; mt < 4; ++mt)
#pragma unroll
                for (int r = 0; r < 4; ++r) {
                    int row = wm + mt * 16 + lq * 4 + r;
                    int col = wn + nt * 16 + lr;
                    float val = acc[mt][nt][r];
                    if (tsel == 0) val *= 0.14724444f;   // SCALE*log2e
                    T[row * 136 + col] = f2bf(val);
                }
    } else {
#pragma unroll
        for (int nt = 0; nt < 4; ++nt)
#pragma unroll
            for (int mt = 0; mt < 4; ++mt)
#pragma unroll
                for (int r = 0; r < 4; ++r) {
                    int row = wm + mt * 16 + lq * 4 + r;   // key token
                    int col = wn + nt * 16 + lr;           // feature
                    T[col * 136 + row] = f2bf(acc[mt][nt][r]);  // transposed
                }
    }
    __syncthreads();
    if (tsel < 2) {
#pragma unroll
        for (int i = 0; i < 8; ++i) {
            int idx = t + i * 256;
            int pos31 = idx & 31;          // store position within 32-group
            int rest = idx >> 5;           // 64 = c8(16) x qg(4)
            int c8 = rest & 15, qg = rest >> 4;
            int l31 = (tsel == 1) ? kperm_inv(pos31) : pos31;  // token row in tile
            int gncol = n0 + c8 * 8;
            int rem = gncol - tsel * 768;
            int head = rem / 96, d = rem - head * 96;
            int kq = d >> 4, h2 = (d >> 3) & 1;
            int gm = m0 + qg * 32 + l31;
            int b = gm >> 12, nn = gm & 4095;
            int bh = b * 8 + head;
            long chunk = (long)(bh * 128 + (nn >> 5)) * 6 + kq;
            ushort8 v8 = *reinterpret_cast<const ushort8*>(&T[(qg * 32 + l31) * 136 + c8 * 8]);
            unsigned short* dst = (tsel == 0) ? Qf : Kf;
            *reinterpret_cast<ushort8*>(&dst[(chunk << 9) + ((h2 * 32 + pos31) << 3)]) = v8;
        }
    } else {
#pragma unroll
        for (int i = 0; i < 8; ++i) {
            int idx = t + i * 256;
            int dl = idx & 31;
            int rr = idx >> 5;             // 64 = r8(16) x cmb(4)
            int r8 = rr & 15, cmb = rr >> 4;
            int col = cmb * 32 + dl;       // feature col within 128-tile
            int gncol = n0 + col;
            int rem = gncol - 1536;
            int head = rem / 96, d = rem - head * 96;
            int dn = d >> 5;               // d&31 == dl
            int keybase = m0 + r8 * 8;     // 8 consecutive keys
            int b = keybase >> 12, nn = keybase & 4095;
            int kg = nn >> 5, f = (nn >> 4) & 1, hv = (nn >> 3) & 1;
            int bh = b * 8 + head;
            long chunk = (long)(bh * 128 + kg) * 6 + dn * 2 + f;
            ushort8 v8 = *reinterpret_cast<const ushort8*>(&T[col * 136 + r8 * 8]);
            *reinterpret_cast<ushort8*>(&Vf[(chunk << 9) + ((hv * 32 + dl) << 3)]) = v8;
        }
    }
}

// ---------------- Flash attention ----------------
// R16 == R14 occupancy restructure, third submission (R4/R5 failed at container
// acquisition with no timing block — infra-level; kernel re-audited twice: bounds,
// barrier uniformity, grid bijectivity, launch_bounds legality all clean). Only
// delta vs R14: exp/pack block expressed as a compact unrolled loop (identical
// semantics and packing order; indices compile-time after unroll) to shrink the
// IR the register allocator processes.
// Theory: R3 is pipe-alternation bound at 2 waves/SIMD (220 combined regs;
// MfmaUtil 38 + VALUBusy 44 = 82%). One 32-row q-chunk per wave: aq 24 VGPR,
// s 16, acc 48 AGPR => ~130 combined; __launch_bounds__(256,4) targets <=128
// -> 4 waves/SIMD (occupancy quantum is 64/128/256, so <=128 is the only
// useful target). Grid 1024 blocks, (b0&7)->XCD mapping keeps 2 bh per XCD
// (3MB K/V in per-XCD L2). Spill tripwire: WRITE_SIZE >> 12.4MB => back off.
__global__ __launch_bounds__(256, 4) void attn_kernel(const unsigned short* __restrict__ Qf,
                                                      const unsigned short* __restrict__ Kf,
                                                      const unsigned short* __restrict__ Vf,
                                                      unsigned short* __restrict__ Og) {
    __shared__ __align__(16) float red[2560];   // 128 lanes x 20 floats (acc exchange + lsum)
    const int t = threadIdx.x;
    const int w = t >> 6, l = t & 63;
    const int wr = w >> 1, wk = w & 1;
    const int l31 = l & 31, h = l >> 5;
    const int b0 = blockIdx.x;                 // 0..1023
    const int kk = b0 >> 3;                    // 0..127
    const int bh = (b0 & 7) * 2 + (kk >> 6);   // XCD-aware: each XCD sees 2 bh
    const int q0 = (kk & 63) * 64;             // 64-row q-tile per block
    const int voff = l << 3;   // lane's ushort offset within a chunk

    bf16x8 aq[6];
    {
        long qb = ((long)((bh * 128 + (q0 >> 5) + wr) * 6)) << 9;
#pragma unroll
        for (int kq = 0; kq < 6; ++kq)
            aq[kq] = *reinterpret_cast<const bf16x8*>(&Qf[qb + (kq << 9) + voff]);
    }

    f32x16 acc[3] = {};   // [dn]
    float lsum = 0.f;     // per-lane denom partial, indexed by q = l31

    for (int it = 0; it < 64; ++it) {
        const int kt = wk * 64 + it;
        const long kbase = ((long)((bh * 128 + kt) * 6)) << 9;
        f32x16 s = {};
#pragma unroll
        for (int kq = 0; kq < 6; ++kq) {
            bf16x8 bk = *reinterpret_cast<const bf16x8*>(&Kf[kbase + (kq << 9) + voff]);
            s = mfma32(bk, aq[kq], s);
        }
        union PF { unsigned int u[4]; bf16x8 v8; } p[2];
#pragma unroll
        for (int g = 0; g < 4; ++g) {
            // group g covers s[4g..4g+3]; packing reproduces the verified R3 e->p map:
            // p[0]: e[0..3] -> u[0],u[1]; e[8..11]  -> u[2],u[3]
            // p[1]: e[4..7] -> u[0],u[1]; e[12..15] -> u[2],u[3]
            float e0 = __builtin_amdgcn_exp2f(s[4 * g + 0]);
            float e1 = __builtin_amdgcn_exp2f(s[4 * g + 1]);
            float e2 = __builtin_amdgcn_exp2f(s[4 * g + 2]);
            float e3 = __builtin_amdgcn_exp2f(s[4 * g + 3]);
            lsum += (e0 + e1) + (e2 + e3);
            p[g & 1].u[(g >> 1) * 2 + 0] = pk2bf(e0, e1);
            p[g & 1].u[(g >> 1) * 2 + 1] = pk2bf(e2, e3);
        }
#pragma unroll
        for (int dn = 0; dn < 3; ++dn) {
#pragma unroll
            for (int f = 0; f < 2; ++f) {
                bf16x8 vb = *reinterpret_cast<const bf16x8*>(
                    &Vf[kbase + ((dn * 2 + f) << 9) + voff]);
                acc[dn] = mfma32(p[f].v8, vb, acc[dn]);
            }
        }
    }

    // ---- cross-wave reduce over wk (pairs share wr; stride 20 floats) ----
    const int rbase = (wr * 64 + l) * 20;
#pragma unroll
    for (int ps = 0; ps < 3; ++ps) {
        __syncthreads();
        if (wk == 1) {
#pragma unroll
            for (int u = 0; u < 4; ++u) {
                f32x4 tmp;
#pragma unroll
                for (int j = 0; j < 4; ++j) tmp[j] = acc[ps][u * 4 + j];
                *reinterpret_cast<f32x4*>(&red[rbase + u * 4]) = tmp;
            }
        }
        __syncthreads();
        if (wk == 0) {
#pragma unroll
            for (int u = 0; u < 4; ++u) {
                f32x4 tmp = *reinterpret_cast<const f32x4*>(&red[rbase + u * 4]);
#pragma unroll
                for (int j = 0; j < 4; ++j) acc[ps][u * 4 + j] += tmp[j];
            }
        }
    }

    // ---- softmax denominator: h-fold in-wave, wk-fold + transpose via LDS ----
    lsum += __shfl_xor(lsum, 32);
    __syncthreads();                      // pass-3 reads above complete
    if (wk == 1 && h == 0) red[wr * 32 + l31] = lsum;
    __syncthreads();
    if (wk == 0 && h == 0)
        red[64 + wr * 32 + l31] = 1.f / (lsum + red[wr * 32 + l31]);
    __syncthreads();
    if (wk == 0) {
        const int b = bh >> 3, head = bh & 7;
#pragma unroll
        for (int reg = 0; reg < 16; ++reg) {
            int qloc = (reg & 3) + 8 * (reg >> 2) + 4 * h;
            int n = q0 + wr * 32 + qloc;
            float inv = red[64 + wr * 32 + qloc];
            int rowoff = (b * 4096 + n) * 768 + head * 96;
#pragma unroll
            for (int dn = 0; dn < 3; ++dn)
                Og[rowoff + dn * 32 + l31] = f2bf(acc[dn][reg] * inv);
        }
    }
}

// ---------------- proj GEMM: [8192x768] x [768x768]^T -> FP32 out ----------------
__global__ __launch_bounds__(256) void proj_gemm(const unsigned short* __restrict__ A,
                                                 const unsigned short* __restrict__ W,
                                                 float* __restrict__ out) {
    __shared__ __align__(16) unsigned short As[128 * 32];
    __shared__ __align__(16) unsigned short Bs[128 * 32];
    const int t = threadIdx.x;
    const int w = t >> 6, l = t & 63;
    const int wm = (w >> 1) * 64, wn = (w & 1) * 64;
    const int lr = l & 15, lq = l >> 4;
    const int m0 = blockIdx.y * 128, n0 = blockIdx.x * 128;
    f32x4 acc[4][4] = {};
    for (int k0 = 0; k0 < 768; k0 += 32) {
        __syncthreads();
#pragma unroll
        for (int i = 0; i < 2; ++i) {
            int v = t + i * 256;
            int r = v >> 2, c8 = (v & 3) * 8;
#if GLL_LANE
            gload16(&A[(m0 + r) * 768 + k0 + c8], &As[(w * 64 + i * 256) * 8]);
            gload16(&W[(n0 + r) * 768 + k0 + c8], &Bs[(w * 64 + i * 256) * 8]);
#else
            *reinterpret_cast<ushort8*>(&As[r * 32 + c8]) =
                *reinterpret_cast<const ushort8*>(&A[(m0 + r) * 768 + k0 + c8]);
            *reinterpret_cast<ushort8*>(&Bs[r * 32 + c8]) =
                *reinterpret_cast<const ushort8*>(&W[(n0 + r) * 768 + k0 + c8]);
#endif
        }
        __syncthreads();
        bf16x8 af[4], bfr[4];
#pragma unroll
        for (int mt = 0; mt < 4; ++mt)
            af[mt] = *reinterpret_cast<const bf16x8*>(&As[(wm + mt * 16 + lr) * 32 + lq * 8]);
#pragma unroll
        for (int nt = 0; nt < 4; ++nt)
            bfr[nt] = *reinterpret_cast<const bf16x8*>(&Bs[(wn + nt * 16 + lr) * 32 + lq * 8]);
#pragma unroll
        for (int mt = 0; mt < 4; ++mt)
#pragma unroll
            for (int nt = 0; nt < 4; ++nt)
                acc[mt][nt] = mfma16(af[mt], bfr[nt], acc[mt][nt]);
    }
#pragma unroll
    for (int nt = 0; nt < 4; ++nt) {
        int gn = n0 + wn + nt * 16 + lr;
#pragma unroll
        for (int mt = 0; mt < 4; ++mt) {
#pragma unroll
            for (int r = 0; r < 4; ++r) {
                int gm = m0 + wm + mt * 16 + lq * 4 + r;
                out[gm * 768 + gn] = acc[mt][nt][r];
            }
        }
    }
}

extern "C" void kernel_launch(void* const* d_in, const int* in_sizes, int n_in,
                              void* d_out, int out_size, void* d_ws, size_t ws_size,
                              hipStream_t stream) {
    const float* x     = (const float*)d_in[0];   // [2,4096,768] fp32
    const float* wqkv  = (const float*)d_in[1];   // [2304,768] fp32
    const float* wproj = (const float*)d_in[2];   // [768,768] fp32
    float* out = (float*)d_out;                   // fp32 [2,4096,768]
    char* ws = (char*)d_ws;
    unsigned short* xb     = (unsigned short*)(ws);             // 12582912
    unsigned short* wqkvb  = (unsigned short*)(ws + 12582912);  // 3538944
    unsigned short* wprojb = (unsigned short*)(ws + 16121856);  // 1179648
    unsigned short* Qf     = (unsigned short*)(ws + 17301504);  // frag chunks
    unsigned short* Kf     = (unsigned short*)(ws + 29884416);  // frag chunks
    unsigned short* Vf     = (unsigned short*)(ws + 42467328);  // frag chunks
    unsigned short* attnb  = xb;                                // reuse: [B,N,C] bf16

    cvt3_f32_bf16<<<8448, 256, 0, stream>>>(x, wqkv, wproj, xb, wqkvb, wprojb);
    qkv_gemm<<<dim3(18, 64), 256, 0, stream>>>(xb, wqkvb, Qf, Kf, Vf);
    attn_kernel<<<1024, 256, 0, stream>>>(Qf, Kf, Vf, attnb);
    proj_gemm<<<dim3(6, 64), 256, 0, stream>>>(attnb, wprojb, out);
}

// Round 7
// 269.168 us; speedup vs baseline: 1.0729x; 1.0729x over previous
//
#include <hip/hip_runtime.h>

typedef __bf16 bf16;
typedef __attribute__((ext_vector_type(8))) __bf16 bf16x8;
typedef __attribute__((ext_vector_type(2))) __bf16 bf16x2;
typedef __attribute__((ext_vector_type(4))) float f32x4;
typedef __attribute__((ext_vector_type(16))) float f32x16;
typedef __attribute__((ext_vector_type(8))) unsigned short ushort8;   // 16B
typedef __attribute__((ext_vector_type(4))) unsigned short ushort4v;  // 8B

__device__ __forceinline__ unsigned short f2bf(float f) {
    union { float f; unsigned int u; } v; v.f = f;
    unsigned int u = v.u;
    return (unsigned short)((u + 0x7fffu + ((u >> 16) & 1u)) >> 16);
}

#if __has_builtin(__builtin_amdgcn_cvt_pk_bf16_f32)
__device__ __forceinline__ unsigned int pk2bf(float a, float b) {
    union { bf16x2 v; unsigned int u; } c;
    c.v = __builtin_amdgcn_cvt_pk_bf16_f32(a, b);
    return c.u;
}
#else
__device__ __forceinline__ unsigned int pk2bf(float a, float b) {
    return (unsigned int)f2bf(a) | ((unsigned int)f2bf(b) << 16);
}
#endif

__device__ __forceinline__ f32x4 mfma16(bf16x8 a, bf16x8 b, f32x4 c) {
    return __builtin_amdgcn_mfma_f32_16x16x32_bf16(a, b, c, 0, 0, 0);
}
__device__ __forceinline__ f32x16 mfma32(bf16x8 a, bf16x8 b, f32x16 c) {
    return __builtin_amdgcn_mfma_f32_32x32x16_bf16(a, b, c, 0, 0, 0);
}

// async global->LDS 16B: HW places lane i's data at ldsbase + i*16 (wave-uniform base).
#if __has_builtin(__builtin_amdgcn_global_load_lds)
__device__ __forceinline__ void gload16(const unsigned short* g, unsigned short* l) {
    typedef const unsigned int __attribute__((address_space(1)))* gp_t;
    typedef unsigned int __attribute__((address_space(3)))* lp_t;
    __builtin_amdgcn_global_load_lds((gp_t)(const void*)g, (lp_t)(void*)l, 16, 0, 0);
}
#define GLL_LANE 1
#else
#define GLL_LANE 0
#endif

// ---------------- fused fp32 -> bf16 convert ----------------
__global__ void cvt3_f32_bf16(const float* __restrict__ x, const float* __restrict__ wq,
                              const float* __restrict__ wp,
                              unsigned short* __restrict__ xb, unsigned short* __restrict__ wqb,
                              unsigned short* __restrict__ wpb) {
    int i = blockIdx.x * 256 + threadIdx.x;   // float4 index
    const float* in; unsigned short* out; int base;
    if (i < 1572864)      { in = x;  out = xb;  base = i; }
    else if (i < 2015232) { in = wq; out = wqb; base = i - 1572864; }
    else if (i < 2162688) { in = wp; out = wpb; base = i - 2015232; }
    else return;
    float4 f = reinterpret_cast<const float4*>(in)[base];
    union { ushort4v v; unsigned int u[2]; } o;
    o.u[0] = pk2bf(f.x, f.y);
    o.u[1] = pk2bf(f.z, f.w);
    reinterpret_cast<ushort4v*>(out)[base] = o.v;
}

// key permutation for 32x32 S^T C-layout -> PV A-layout:  p: a -> bits (a0,a1,a3,a4,a2)
__device__ __forceinline__ int kperm(int k5) {
    return (k5 & 3) | (((k5 >> 3) & 1) << 2) | (((k5 >> 4) & 1) << 3) | (((k5 >> 2) & 1) << 4);
}
__device__ __forceinline__ int kperm_inv(int p5) {
    return (p5 & 3) | (((p5 >> 4) & 1) << 2) | (((p5 >> 2) & 1) << 3) | (((p5 >> 3) & 1) << 4);
}

// ---------------- QKV GEMM -> fragment-ready chunked layouts ----------------
// R17: BK 32->64 via two 32-col subtiles (As0/As1, Bs0/Bs1, each 128x32 stride-64B).
// Halves K-loop barrier count (24 steps -> 12). Row stride stays 64B (same bank behavior
// as the verified BK=32 layout; a naive 128B-stride tile would be a 32-way conflict, G4).
// gload_lds dest stays wave-linear: each wave's 64 chunks lie within one subtile.
// Fragment reads in two register-reusing halves -> no extra register pressure.
// Accumulate order over k is unchanged -> bit-identical acc. Epilogue untouched.
__global__ __launch_bounds__(256) void qkv_gemm(const unsigned short* __restrict__ A,
                                                const unsigned short* __restrict__ W,
                                                unsigned short* __restrict__ Qf,
                                                unsigned short* __restrict__ Kf,
                                                unsigned short* __restrict__ Vf) {
    __shared__ __align__(16) char smem[34816];
    unsigned short* As = (unsigned short*)smem;   // As0[0,4096) As1[4096,8192) Bs0[8192,12288) Bs1[12288,16384)
    unsigned short* T  = (unsigned short*)smem;   // epilogue tile 128x136 (34816 B)
    const int t = threadIdx.x;
    const int w = t >> 6, l = t & 63;
    const int wm = (w >> 1) * 64, wn = (w & 1) * 64;
    const int lr = l & 15, lq = l >> 4;
    const int m0 = blockIdx.y * 128, n0 = blockIdx.x * 128;
    f32x4 acc[4][4] = {};
    for (int k0 = 0; k0 < 768; k0 += 64) {
        __syncthreads();
#pragma unroll
        for (int i = 0; i < 4; ++i) {
            int v = t + i * 256;          // 0..1023 chunk id
            int sub = v >> 9;             // 0: cols k0..k0+31, 1: cols k0+32..k0+63
            int vin = v & 511;
            int r = vin >> 2, c8 = (vin & 3) * 8;
            int gcol = k0 + sub * 32 + c8;
#if GLL_LANE
            int vbase = w * 64 + i * 256;                       // wave-uniform
            int subu = vbase >> 9;
            unsigned short* dA = &As[subu * 4096 + (vbase & 511) * 8];
            gload16(&A[(m0 + r) * 768 + gcol], dA);
            gload16(&W[(n0 + r) * 768 + gcol], dA + 8192);
#else
            *reinterpret_cast<ushort8*>(&As[sub * 4096 + vin * 8]) =
                *reinterpret_cast<const ushort8*>(&A[(m0 + r) * 768 + gcol]);
            *reinterpret_cast<ushort8*>(&As[8192 + sub * 4096 + vin * 8]) =
                *reinterpret_cast<const ushort8*>(&W[(n0 + r) * 768 + gcol]);
#endif
        }
        __syncthreads();   // compiler drains vmcnt(0) before s_barrier -> LDS data visible
        bf16x8 af[4], bfr[4];
        // ---- k-half 0 (cols k0..k0+31) ----
#pragma unroll
        for (int mt = 0; mt < 4; ++mt)
            af[mt] = *reinterpret_cast<const bf16x8*>(&As[(wm + mt * 16 + lr) * 32 + lq * 8]);
#pragma unroll
        for (int nt = 0; nt < 4; ++nt)
            bfr[nt] = *reinterpret_cast<const bf16x8*>(&As[8192 + (wn + nt * 16 + lr) * 32 + lq * 8]);
#pragma unroll
        for (int mt = 0; mt < 4; ++mt)
#pragma unroll
            for (int nt = 0; nt < 4; ++nt)
                acc[mt][nt] = mfma16(af[mt], bfr[nt], acc[mt][nt]);
        // ---- k-half 1 (cols k0+32..k0+63), reuse fragment registers ----
#pragma unroll
        for (int mt = 0; mt < 4; ++mt)
            af[mt] = *reinterpret_cast<const bf16x8*>(&As[4096 + (wm + mt * 16 + lr) * 32 + lq * 8]);
#pragma unroll
        for (int nt = 0; nt < 4; ++nt)
            bfr[nt] = *reinterpret_cast<const bf16x8*>(&As[12288 + (wn + nt * 16 + lr) * 32 + lq * 8]);
#pragma unroll
        for (int mt = 0; mt < 4; ++mt)
#pragma unroll
            for (int nt = 0; nt < 4; ++nt)
                acc[mt][nt] = mfma16(af[mt], bfr[nt], acc[mt][nt]);
    }
    // ---- epilogue: C tile -> LDS (V region transposed) -> coalesced b128 stores ----
    const int tsel = n0 / 768;   // whole block is one of Q/K/V
    __syncthreads();             // fragment reads done; reuse smem as T
    if (tsel < 2) {
#pragma unroll
        for (int nt = 0; nt < 4; ++nt)
#pragma unroll
            for (int mt = 0; mt < 4; ++mt)
#pragma unroll
                for (int r = 0; r < 4; ++r) {
                    int row = wm + mt * 16 + lq * 4 + r;
                    int col = wn + nt * 16 + lr;
                    float val = acc[mt][nt][r];
                    if (tsel == 0) val *= 0.14724444f;   // SCALE*log2e
                    T[row * 136 + col] = f2bf(val);
                }
    } else {
#pragma unroll
        for (int nt = 0; nt < 4; ++nt)
#pragma unroll
            for (int mt = 0; mt < 4; ++mt)
#pragma unroll
                for (int r = 0; r < 4; ++r) {
                    int row = wm + mt * 16 + lq * 4 + r;   // key token
                    int col = wn + nt * 16 + lr;           // feature
                    T[col * 136 + row] = f2bf(acc[mt][nt][r]);  // transposed
                }
    }
    __syncthreads();
    if (tsel < 2) {
#pragma unroll
        for (int i = 0; i < 8; ++i) {
            int idx = t + i * 256;
            int pos31 = idx & 31;          // store position within 32-group
            int rest = idx >> 5;           // 64 = c8(16) x qg(4)
            int c8 = rest & 15, qg = rest >> 4;
            int l31 = (tsel == 1) ? kperm_inv(pos31) : pos31;  // token row in tile
            int gncol = n0 + c8 * 8;
            int rem = gncol - tsel * 768;
            int head = rem / 96, d = rem - head * 96;
            int kq = d >> 4, h2 = (d >> 3) & 1;
            int gm = m0 + qg * 32 + l31;
            int b = gm >> 12, nn = gm & 4095;
            int bh = b * 8 + head;
            long chunk = (long)(bh * 128 + (nn >> 5)) * 6 + kq;
            ushort8 v8 = *reinterpret_cast<const ushort8*>(&T[(qg * 32 + l31) * 136 + c8 * 8]);
            unsigned short* dst = (tsel == 0) ? Qf : Kf;
            *reinterpret_cast<ushort8*>(&dst[(chunk << 9) + ((h2 * 32 + pos31) << 3)]) = v8;
        }
    } else {
#pragma unroll
        for (int i = 0; i < 8; ++i) {
            int idx = t + i * 256;
            int dl = idx & 31;
            int rr = idx >> 5;             // 64 = r8(16) x cmb(4)
            int r8 = rr & 15, cmb = rr >> 4;
            int col = cmb * 32 + dl;       // feature col within 128-tile
            int gncol = n0 + col;
            int rem = gncol - 1536;
            int head = rem / 96, d = rem - head * 96;
            int dn = d >> 5;               // d&31 == dl
            int keybase = m0 + r8 * 8;     // 8 consecutive keys
            int b = keybase >> 12, nn = keybase & 4095;
            int kg = nn >> 5, f = (nn >> 4) & 1, hv = (nn >> 3) & 1;
            int bh = b * 8 + head;
            long chunk = (long)(bh * 128 + kg) * 6 + dn * 2 + f;
            ushort8 v8 = *reinterpret_cast<const ushort8*>(&T[col * 136 + r8 * 8]);
            *reinterpret_cast<ushort8*>(&Vf[(chunk << 9) + ((hv * 32 + dl) << 3)]) = v8;
        }
    }
}

// ---------------- Flash attention ----------------
// R17: revert to R3 structure (best measured: 121.7us; R6's occupancy restructure traded
// per-wave ILP for waves and lost 15%). One change vs R3: exp/pack split by f-group and
// interleaved with PV -- exp(f=0, both qn) -> PV f=0 (6 MFMA) -> exp(f=1) -> PV f=1.
// Identical arithmetic/packing to R3's p[qn][f] map; gives the scheduler an explicit
// exp(f=1)||PV(f=0) window and halves p liveness. Zero register cost.
__global__ __launch_bounds__(256, 2) void attn_kernel(const unsigned short* __restrict__ Qf,
                                                      const unsigned short* __restrict__ Kf,
                                                      const unsigned short* __restrict__ Vf,
                                                      unsigned short* __restrict__ Og) {
    __shared__ __align__(16) float red[4608];   // 128 x 36 epilogue reduce (+ lsum scratch)
    const int t = threadIdx.x;
    const int w = t >> 6, l = t & 63;
    const int wr = w >> 1, wk = w & 1;
    const int l31 = l & 31, h = l >> 5;
    const int b0 = blockIdx.x;
    const int kk = b0 >> 3;
    const int bh = (b0 & 7) * 2 + (kk >> 5);
    const int q0 = (kk & 31) * 128;
    const int voff = l << 3;   // lane's ushort offset within a chunk

    bf16x8 aq[2][6];
#pragma unroll
    for (int qn = 0; qn < 2; ++qn) {
        long qb = ((long)((bh * 128 + (q0 >> 5) + wr * 2 + qn) * 6)) << 9;
#pragma unroll
        for (int kq = 0; kq < 6; ++kq)
            aq[qn][kq] = *reinterpret_cast<const bf16x8*>(&Qf[qb + (kq << 9) + voff]);
    }

    f32x16 acc[2][3] = {};   // [qn][dn]
    float lsum0 = 0.f, lsum1 = 0.f;   // per-lane denom partial, indexed by q = l31

    for (int it = 0; it < 64; ++it) {
        const int kt = wk * 64 + it;
        const long kbase = ((long)((bh * 128 + kt) * 6)) << 9;
        f32x16 s[2] = {};
#pragma unroll
        for (int kq = 0; kq < 6; ++kq) {
            bf16x8 bk = *reinterpret_cast<const bf16x8*>(&Kf[kbase + (kq << 9) + voff]);
            s[0] = mfma32(bk, aq[0][kq], s[0]);
            s[1] = mfma32(bk, aq[1][kq], s[1]);
        }
        union PF { unsigned int u[4]; bf16x8 v8; } p0[2], p1[2];
        // ---- f=0 exps (e[0..3], e[8..11] of each qn) ----
#pragma unroll
        for (int qn = 0; qn < 2; ++qn) {
            float ea = __builtin_amdgcn_exp2f(s[qn][0]);
            float eb = __builtin_amdgcn_exp2f(s[qn][1]);
            float ec = __builtin_amdgcn_exp2f(s[qn][2]);
            float ed = __builtin_amdgcn_exp2f(s[qn][3]);
            float ee = __builtin_amdgcn_exp2f(s[qn][8]);
            float ef = __builtin_amdgcn_exp2f(s[qn][9]);
            float eg = __builtin_amdgcn_exp2f(s[qn][10]);
            float eh = __builtin_amdgcn_exp2f(s[qn][11]);
            float part = ((ea + eb) + (ec + ed)) + ((ee + ef) + (eg + eh));
            if (qn == 0) lsum0 += part; else lsum1 += part;
            p0[qn].u[0] = pk2bf(ea, eb); p0[qn].u[1] = pk2bf(ec, ed);
            p0[qn].u[2] = pk2bf(ee, ef); p0[qn].u[3] = pk2bf(eg, eh);
        }
        // ---- PV f=0 (scheduler can start these while f=1 exps issue below) ----
#pragma unroll
        for (int dn = 0; dn < 3; ++dn) {
            bf16x8 vb = *reinterpret_cast<const bf16x8*>(
                &Vf[kbase + ((dn * 2) << 9) + voff]);
            acc[0][dn] = mfma32(p0[0].v8, vb, acc[0][dn]);
            acc[1][dn] = mfma32(p0[1].v8, vb, acc[1][dn]);
        }
        // ---- f=1 exps (e[4..7], e[12..15]) ----
#pragma unroll
        for (int qn = 0; qn < 2; ++qn) {
            float ea = __builtin_amdgcn_exp2f(s[qn][4]);
            float eb = __builtin_amdgcn_exp2f(s[qn][5]);
            float ec = __builtin_amdgcn_exp2f(s[qn][6]);
            float ed = __builtin_amdgcn_exp2f(s[qn][7]);
            float ee = __builtin_amdgcn_exp2f(s[qn][12]);
            float ef = __builtin_amdgcn_exp2f(s[qn][13]);
            float eg = __builtin_amdgcn_exp2f(s[qn][14]);
            float eh = __builtin_amdgcn_exp2f(s[qn][15]);
            float part = ((ea + eb) + (ec + ed)) + ((ee + ef) + (eg + eh));
            if (qn == 0) lsum0 += part; else lsum1 += part;
            p1[qn].u[0] = pk2bf(ea, eb); p1[qn].u[1] = pk2bf(ec, ed);
            p1[qn].u[2] = pk2bf(ee, ef); p1[qn].u[3] = pk2bf(eg, eh);
        }
        // ---- PV f=1 ----
#pragma unroll
        for (int dn = 0; dn < 3; ++dn) {
            bf16x8 vb = *reinterpret_cast<const bf16x8*>(
                &Vf[kbase + ((dn * 2 + 1) << 9) + voff]);
            acc[0][dn] = mfma32(p1[0].v8, vb, acc[0][dn]);
            acc[1][dn] = mfma32(p1[1].v8, vb, acc[1][dn]);
        }
    }

    // ---- cross-wave reduce over wk (pairs, stride 36 floats) ----
    const int rbase = (wr * 64 + l) * 36;
#pragma unroll
    for (int ps = 0; ps < 3; ++ps) {
        __syncthreads();
        if (wk == 1) {
#pragma unroll
            for (int c = 0; c < 2; ++c) {
                int c2 = ps * 2 + c, qn = c2 / 3, dn = c2 % 3;
#pragma unroll
                for (int u = 0; u < 4; ++u) {
                    f32x4 tmp;
#pragma unroll
                    for (int j = 0; j < 4; ++j) tmp[j] = acc[qn][dn][u * 4 + j];
                    *reinterpret_cast<f32x4*>(&red[rbase + c * 16 + u * 4]) = tmp;
                }
            }
        }
        __syncthreads();
        if (wk == 0) {
#pragma unroll
            for (int c = 0; c < 2; ++c) {
                int c2 = ps * 2 + c, qn = c2 / 3, dn = c2 % 3;
#pragma unroll
                for (int u = 0; u < 4; ++u) {
                    f32x4 tmp = *reinterpret_cast<const f32x4*>(&red[rbase + c * 16 + u * 4]);
#pragma unroll
                    for (int j = 0; j < 4; ++j) acc[qn][dn][u * 4 + j] += tmp[j];
                }
            }
        }
    }

    // ---- softmax denominator: h-fold in-wave, wk-fold + transpose via LDS ----
    lsum0 += __shfl_xor(lsum0, 32);
    lsum1 += __shfl_xor(lsum1, 32);
    __syncthreads();                      // phase-3 reads above complete
    if (wk == 1 && h == 0) {
        red[(wr * 2 + 0) * 32 + l31] = lsum0;
        red[(wr * 2 + 1) * 32 + l31] = lsum1;
    }
    __syncthreads();
    if (wk == 0 && h == 0) {
        red[128 + (wr * 2 + 0) * 32 + l31] = 1.f / (lsum0 + red[(wr * 2 + 0) * 32 + l31]);
        red[128 + (wr * 2 + 1) * 32 + l31] = 1.f / (lsum1 + red[(wr * 2 + 1) * 32 + l31]);
    }
    __syncthreads();
    if (wk == 0) {
        const int b = bh >> 3, head = bh & 7;
#pragma unroll
        for (int qn = 0; qn < 2; ++qn) {
#pragma unroll
            for (int reg = 0; reg < 16; ++reg) {
                int qloc = (reg & 3) + 8 * (reg >> 2) + 4 * h;
                int n = q0 + wr * 64 + qn * 32 + qloc;
                float inv = red[128 + (wr * 2 + qn) * 32 + qloc];
                int rowoff = (b * 4096 + n) * 768 + head * 96;
#pragma unroll
                for (int dn = 0; dn < 3; ++dn)
                    Og[rowoff + dn * 32 + l31] = f2bf(acc[qn][dn][reg] * inv);
            }
        }
    }
}

// ---------------- proj GEMM: [8192x768] x [768x768]^T -> FP32 out ----------------
// R17: same BK=64 two-subtile restructure as qkv_gemm.
__global__ __launch_bounds__(256) void proj_gemm(const unsigned short* __restrict__ A,
                                                 const unsigned short* __restrict__ W,
                                                 float* __restrict__ out) {
    __shared__ __align__(16) unsigned short As[16384];  // As0/As1/Bs0/Bs1, 4x8KB
    const int t = threadIdx.x;
    const int w = t >> 6, l = t & 63;
    const int wm = (w >> 1) * 64, wn = (w & 1) * 64;
    const int lr = l & 15, lq = l >> 4;
    const int m0 = blockIdx.y * 128, n0 = blockIdx.x * 128;
    f32x4 acc[4][4] = {};
    for (int k0 = 0; k0 < 768; k0 += 64) {
        __syncthreads();
#pragma unroll
        for (int i = 0; i < 4; ++i) {
            int v = t + i * 256;
            int sub = v >> 9;
            int vin = v & 511;
            int r = vin >> 2, c8 = (vin & 3) * 8;
            int gcol = k0 + sub * 32 + c8;
#if GLL_LANE
            int vbase = w * 64 + i * 256;
            int subu = vbase >> 9;
            unsigned short* dA = &As[subu * 4096 + (vbase & 511) * 8];
            gload16(&A[(m0 + r) * 768 + gcol], dA);
            gload16(&W[(n0 + r) * 768 + gcol], dA + 8192);
#else
            *reinterpret_cast<ushort8*>(&As[sub * 4096 + vin * 8]) =
                *reinterpret_cast<const ushort8*>(&A[(m0 + r) * 768 + gcol]);
            *reinterpret_cast<ushort8*>(&As[8192 + sub * 4096 + vin * 8]) =
                *reinterpret_cast<const ushort8*>(&W[(n0 + r) * 768 + gcol]);
#endif
        }
        __syncthreads();
        bf16x8 af[4], bfr[4];
#pragma unroll
        for (int mt = 0; mt < 4; ++mt)
            af[mt] = *reinterpret_cast<const bf16x8*>(&As[(wm + mt * 16 + lr) * 32 + lq * 8]);
#pragma unroll
        for (int nt = 0; nt < 4; ++nt)
            bfr[nt] = *reinterpret_cast<const bf16x8*>(&As[8192 + (wn + nt * 16 + lr) * 32 + lq * 8]);
#pragma unroll
        for (int mt = 0; mt < 4; ++mt)
#pragma unroll
            for (int nt = 0; nt < 4; ++nt)
                acc[mt][nt] = mfma16(af[mt], bfr[nt], acc[mt][nt]);
#pragma unroll
        for (int mt = 0; mt < 4; ++mt)
            af[mt] = *reinterpret_cast<const bf16x8*>(&As[4096 + (wm + mt * 16 + lr) * 32 + lq * 8]);
#pragma unroll
        for (int nt = 0; nt < 4; ++nt)
            bfr[nt] = *reinterpret_cast<const bf16x8*>(&As[12288 + (wn + nt * 16 + lr) * 32 + lq * 8]);
#pragma unroll
        for (int mt = 0; mt < 4; ++mt)
#pragma unroll
            for (int nt = 0; nt < 4; ++nt)
                acc[mt][nt] = mfma16(af[mt], bfr[nt], acc[mt][nt]);
    }
#pragma unroll
    for (int nt = 0; nt < 4; ++nt) {
        int gn = n0 + wn + nt * 16 + lr;
#pragma unroll
        for (int mt = 0; mt < 4; ++mt) {
#pragma unroll
            for (int r = 0; r < 4; ++r) {
                int gm = m0 + wm + mt * 16 + lq * 4 + r;
                out[gm * 768 + gn] = acc[mt][nt][r];
            }
        }
    }
}

extern "C" void kernel_launch(void* const* d_in, const int* in_sizes, int n_in,
                              void* d_out, int out_size, void* d_ws, size_t ws_size,
                              hipStream_t stream) {
    const float* x     = (const float*)d_in[0];   // [2,4096,768] fp32
    const float* wqkv  = (const float*)d_in[1];   // [2304,768] fp32
    const float* wproj = (const float*)d_in[2];   // [768,768] fp32
    float* out = (float*)d_out;                   // fp32 [2,4096,768]
    char* ws = (char*)d_ws;
    unsigned short* xb     = (unsigned short*)(ws);             // 12582912
    unsigned short* wqkvb  = (unsigned short*)(ws + 12582912);  // 3538944
    unsigned short* wprojb = (unsigned short*)(ws + 16121856);  // 1179648
    unsigned short* Qf     = (unsigned short*)(ws + 17301504);  // frag chunks
    unsigned short* Kf     = (unsigned short*)(ws + 29884416);  // frag chunks
    unsigned short* Vf     = (unsigned short*)(ws + 42467328);  // frag chunks
    unsigned short* attnb  = xb;                                // reuse: [B,N,C] bf16

    cvt3_f32_bf16<<<8448, 256, 0, stream>>>(x, wqkv, wproj, xb, wqkvb, wprojb);
    qkv_gemm<<<dim3(18, 64), 256, 0, stream>>>(xb, wqkvb, Qf, Kf, Vf);
    attn_kernel<<<512, 256, 0, stream>>>(Qf, Kf, Vf, attnb);
    proj_gemm<<<dim3(6, 64), 256, 0, stream>>>(attnb, wprojb, out);
}

// Round 8
// 262.018 us; speedup vs baseline: 1.1022x; 1.0273x over previous
//
#include <hip/hip_runtime.h>

typedef __bf16 bf16;
typedef __attribute__((ext_vector_type(8))) __bf16 bf16x8;
typedef __attribute__((ext_vector_type(2))) __bf16 bf16x2;
typedef __attribute__((ext_vector_type(4))) float f32x4;
typedef __attribute__((ext_vector_type(16))) float f32x16;
typedef __attribute__((ext_vector_type(8))) unsigned short ushort8;   // 16B
typedef __attribute__((ext_vector_type(4))) unsigned short ushort4v;  // 8B

__device__ __forceinline__ unsigned short f2bf(float f) {
    union { float f; unsigned int u; } v; v.f = f;
    unsigned int u = v.u;
    return (unsigned short)((u + 0x7fffu + ((u >> 16) & 1u)) >> 16);
}

#if __has_builtin(__builtin_amdgcn_cvt_pk_bf16_f32)
__device__ __forceinline__ unsigned int pk2bf(float a, float b) {
    union { bf16x2 v; unsigned int u; } c;
    c.v = __builtin_amdgcn_cvt_pk_bf16_f32(a, b);
    return c.u;
}
#else
__device__ __forceinline__ unsigned int pk2bf(float a, float b) {
    return (unsigned int)f2bf(a) | ((unsigned int)f2bf(b) << 16);
}
#endif

__device__ __forceinline__ f32x4 mfma16(bf16x8 a, bf16x8 b, f32x4 c) {
    return __builtin_amdgcn_mfma_f32_16x16x32_bf16(a, b, c, 0, 0, 0);
}
__device__ __forceinline__ f32x16 mfma32(bf16x8 a, bf16x8 b, f32x16 c) {
    return __builtin_amdgcn_mfma_f32_32x32x16_bf16(a, b, c, 0, 0, 0);
}

// async global->LDS 16B: HW places lane i's data at ldsbase + i*16 (wave-uniform base).
#if __has_builtin(__builtin_amdgcn_global_load_lds)
__device__ __forceinline__ void gload16(const unsigned short* g, unsigned short* l) {
    typedef const unsigned int __attribute__((address_space(1)))* gp_t;
    typedef unsigned int __attribute__((address_space(3)))* lp_t;
    __builtin_amdgcn_global_load_lds((gp_t)(const void*)g, (lp_t)(void*)l, 16, 0, 0);
}
#define GLL_LANE 1
#else
#define GLL_LANE 0
#endif

// ---------------- fused fp32 -> bf16 convert ----------------
__global__ void cvt3_f32_bf16(const float* __restrict__ x, const float* __restrict__ wq,
                              const float* __restrict__ wp,
                              unsigned short* __restrict__ xb, unsigned short* __restrict__ wqb,
                              unsigned short* __restrict__ wpb) {
    int i = blockIdx.x * 256 + threadIdx.x;   // float4 index
    const float* in; unsigned short* out; int base;
    if (i < 1572864)      { in = x;  out = xb;  base = i; }
    else if (i < 2015232) { in = wq; out = wqb; base = i - 1572864; }
    else if (i < 2162688) { in = wp; out = wpb; base = i - 2015232; }
    else return;
    float4 f = reinterpret_cast<const float4*>(in)[base];
    union { ushort4v v; unsigned int u[2]; } o;
    o.u[0] = pk2bf(f.x, f.y);
    o.u[1] = pk2bf(f.z, f.w);
    reinterpret_cast<ushort4v*>(out)[base] = o.v;
}

// key permutation for 32x32 S^T C-layout -> PV A-layout:  p: a -> bits (a0,a1,a3,a4,a2)
__device__ __forceinline__ int kperm(int k5) {
    return (k5 & 3) | (((k5 >> 3) & 1) << 2) | (((k5 >> 4) & 1) << 3) | (((k5 >> 2) & 1) << 4);
}
__device__ __forceinline__ int kperm_inv(int p5) {
    return (p5 & 3) | (((p5 >> 4) & 1) << 2) | (((p5 >> 2) & 1) << 3) | (((p5 >> 3) & 1) << 4);
}

// ---------------- QKV GEMM -> fragment-ready chunked layouts ----------------
// R18: 2-phase STAGE-ahead double buffer (T3-minimum). BK=32, two 16KB buffers (A 8KB +
// B 8KB each) = 32KB, fits under the 34.8KB epilogue footprint -> occupancy unchanged.
// Per K-step: issue STAGE(t+1) into the other buffer BEFORE computing tile t; one
// __syncthreads per step (drains vmcnt(0) after compute, so staging latency overlaps
// ds_read+MFMA instead of being fully exposed as in the 2-barrier structure).
// Accumulate order over k unchanged -> bit-identical acc. Epilogue untouched (R3-verified).
__global__ __launch_bounds__(256) void qkv_gemm(const unsigned short* __restrict__ A,
                                                const unsigned short* __restrict__ W,
                                                unsigned short* __restrict__ Qf,
                                                unsigned short* __restrict__ Kf,
                                                unsigned short* __restrict__ Vf) {
    __shared__ __align__(16) char smem[34816];
    unsigned short* S = (unsigned short*)smem;   // dbuf: buf b at ushort off b*8192: A[0,4096) B[4096,8192)
    unsigned short* T = (unsigned short*)smem;   // epilogue tile 128x136 (34816 B), reused after loop
    const int t = threadIdx.x;
    const int w = t >> 6, l = t & 63;
    const int wm = (w >> 1) * 64, wn = (w & 1) * 64;
    const int lr = l & 15, lq = l >> 4;
    const int m0 = blockIdx.y * 128, n0 = blockIdx.x * 128;
    f32x4 acc[4][4] = {};

#if GLL_LANE
#define QSTAGE(ks, boff)                                                        \
    {                                                                           \
        const int k0s = (ks) * 32;                                              \
        _Pragma("unroll")                                                       \
        for (int i = 0; i < 2; ++i) {                                           \
            int v = t + i * 256;                                                \
            int r = v >> 2, c8 = (v & 3) * 8;                                   \
            unsigned short* dst = &S[(boff) + (w * 64 + i * 256) * 8];          \
            gload16(&A[(m0 + r) * 768 + k0s + c8], dst);                        \
            gload16(&W[(n0 + r) * 768 + k0s + c8], dst + 4096);                 \
        }                                                                       \
    }
#else
#define QSTAGE(ks, boff)                                                        \
    {                                                                           \
        const int k0s = (ks) * 32;                                              \
        _Pragma("unroll")                                                       \
        for (int i = 0; i < 2; ++i) {                                           \
            int v = t + i * 256;                                                \
            int r = v >> 2, c8 = (v & 3) * 8;                                   \
            *reinterpret_cast<ushort8*>(&S[(boff) + v * 8]) =                   \
                *reinterpret_cast<const ushort8*>(&A[(m0 + r) * 768 + k0s + c8]);\
            *reinterpret_cast<ushort8*>(&S[(boff) + 4096 + v * 8]) =            \
                *reinterpret_cast<const ushort8*>(&W[(n0 + r) * 768 + k0s + c8]);\
        }                                                                       \
    }
#endif

    QSTAGE(0, 0);
    __syncthreads();   // drains vmcnt(0): buf0 visible
    for (int ks = 0; ks < 24; ++ks) {
        const int cur = (ks & 1) ? 8192 : 0;
        if (ks < 23) QSTAGE(ks + 1, 8192 - cur);   // loads fly during compute below
        bf16x8 af[4], bfr[4];
#pragma unroll
        for (int mt = 0; mt < 4; ++mt)
            af[mt] = *reinterpret_cast<const bf16x8*>(&S[cur + (wm + mt * 16 + lr) * 32 + lq * 8]);
#pragma unroll
        for (int nt = 0; nt < 4; ++nt)
            bfr[nt] = *reinterpret_cast<const bf16x8*>(&S[cur + 4096 + (wn + nt * 16 + lr) * 32 + lq * 8]);
#pragma unroll
        for (int mt = 0; mt < 4; ++mt)
#pragma unroll
            for (int nt = 0; nt < 4; ++nt)
                acc[mt][nt] = mfma16(af[mt], bfr[nt], acc[mt][nt]);
        __syncthreads();   // drains vmcnt(0) (next buf landed) + all reads of cur done
    }
#undef QSTAGE
    // ---- epilogue: C tile -> LDS (V region transposed) -> coalesced b128 stores ----
    const int tsel = n0 / 768;   // whole block is one of Q/K/V
    if (tsel < 2) {
#pragma unroll
        for (int nt = 0; nt < 4; ++nt)
#pragma unroll
            for (int mt = 0; mt < 4; ++mt)
#pragma unroll
                for (int r = 0; r < 4; ++r) {
                    int row = wm + mt * 16 + lq * 4 + r;
                    int col = wn + nt * 16 + lr;
                    float val = acc[mt][nt][r];
                    if (tsel == 0) val *= 0.14724444f;   // SCALE*log2e
                    T[row * 136 + col] = f2bf(val);
                }
    } else {
#pragma unroll
        for (int nt = 0; nt < 4; ++nt)
#pragma unroll
            for (int mt = 0; mt < 4; ++mt)
#pragma unroll
                for (int r = 0; r < 4; ++r) {
                    int row = wm + mt * 16 + lq * 4 + r;   // key token
                    int col = wn + nt * 16 + lr;           // feature
                    T[col * 136 + row] = f2bf(acc[mt][nt][r]);  // transposed
                }
    }
    __syncthreads();
    if (tsel < 2) {
#pragma unroll
        for (int i = 0; i < 8; ++i) {
            int idx = t + i * 256;
            int pos31 = idx & 31;          // store position within 32-group
            int rest = idx >> 5;           // 64 = c8(16) x qg(4)
            int c8 = rest & 15, qg = rest >> 4;
            int l31 = (tsel == 1) ? kperm_inv(pos31) : pos31;  // token row in tile
            int gncol = n0 + c8 * 8;
            int rem = gncol - tsel * 768;
            int head = rem / 96, d = rem - head * 96;
            int kq = d >> 4, h2 = (d >> 3) & 1;
            int gm = m0 + qg * 32 + l31;
            int b = gm >> 12, nn = gm & 4095;
            int bh = b * 8 + head;
            long chunk = (long)(bh * 128 + (nn >> 5)) * 6 + kq;
            ushort8 v8 = *reinterpret_cast<const ushort8*>(&T[(qg * 32 + l31) * 136 + c8 * 8]);
            unsigned short* dst = (tsel == 0) ? Qf : Kf;
            *reinterpret_cast<ushort8*>(&dst[(chunk << 9) + ((h2 * 32 + pos31) << 3)]) = v8;
        }
    } else {
#pragma unroll
        for (int i = 0; i < 8; ++i) {
            int idx = t + i * 256;
            int dl = idx & 31;
            int rr = idx >> 5;             // 64 = r8(16) x cmb(4)
            int r8 = rr & 15, cmb = rr >> 4;
            int col = cmb * 32 + dl;       // feature col within 128-tile
            int gncol = n0 + col;
            int rem = gncol - 1536;
            int head = rem / 96, d = rem - head * 96;
            int dn = d >> 5;               // d&31 == dl
            int keybase = m0 + r8 * 8;     // 8 consecutive keys
            int b = keybase >> 12, nn = keybase & 4095;
            int kg = nn >> 5, f = (nn >> 4) & 1, hv = (nn >> 3) & 1;
            int bh = b * 8 + head;
            long chunk = (long)(bh * 128 + kg) * 6 + dn * 2 + f;
            ushort8 v8 = *reinterpret_cast<const ushort8*>(&T[col * 136 + r8 * 8]);
            *reinterpret_cast<ushort8*>(&Vf[(chunk << 9) + ((hv * 32 + dl) << 3)]) = v8;
        }
    }
}

// ---------------- Flash attention ----------------
// R18: exact R3 loop (best measured 121.7us). R7's exp f-split regressed +2.9us -> reverted.
// lsum VALU denominator kept (verified win). No setprio (R2 lesson). No dbuf (R1 lesson).
__global__ __launch_bounds__(256, 2) void attn_kernel(const unsigned short* __restrict__ Qf,
                                                      const unsigned short* __restrict__ Kf,
                                                      const unsigned short* __restrict__ Vf,
                                                      unsigned short* __restrict__ Og) {
    __shared__ __align__(16) float red[4608];   // 128 x 36 epilogue reduce (+ lsum scratch)
    const int t = threadIdx.x;
    const int w = t >> 6, l = t & 63;
    const int wr = w >> 1, wk = w & 1;
    const int l31 = l & 31, h = l >> 5;
    const int b0 = blockIdx.x;
    const int kk = b0 >> 3;
    const int bh = (b0 & 7) * 2 + (kk >> 5);
    const int q0 = (kk & 31) * 128;
    const int voff = l << 3;   // lane's ushort offset within a chunk

    bf16x8 aq[2][6];
#pragma unroll
    for (int qn = 0; qn < 2; ++qn) {
        long qb = ((long)((bh * 128 + (q0 >> 5) + wr * 2 + qn) * 6)) << 9;
#pragma unroll
        for (int kq = 0; kq < 6; ++kq)
            aq[qn][kq] = *reinterpret_cast<const bf16x8*>(&Qf[qb + (kq << 9) + voff]);
    }

    f32x16 acc[2][3] = {};   // [qn][dn]
    float lsum0 = 0.f, lsum1 = 0.f;   // per-lane denom partial, indexed by q = l31

    for (int it = 0; it < 64; ++it) {
        const int kt = wk * 64 + it;
        const long kbase = ((long)((bh * 128 + kt) * 6)) << 9;
        f32x16 s[2] = {};
#pragma unroll
        for (int kq = 0; kq < 6; ++kq) {
            bf16x8 bk = *reinterpret_cast<const bf16x8*>(&Kf[kbase + (kq << 9) + voff]);
            s[0] = mfma32(bk, aq[0][kq], s[0]);
            s[1] = mfma32(bk, aq[1][kq], s[1]);
        }
        union PF { unsigned int u[4]; bf16x8 v8; } p[2][2];
#pragma unroll
        for (int qn = 0; qn < 2; ++qn) {
            float e[16];
#pragma unroll
            for (int r = 0; r < 16; ++r) e[r] = __builtin_amdgcn_exp2f(s[qn][r]);
            float s0 = (e[0] + e[1]) + (e[2] + e[3]);
            float s1 = (e[4] + e[5]) + (e[6] + e[7]);
            float s2 = (e[8] + e[9]) + (e[10] + e[11]);
            float s3 = (e[12] + e[13]) + (e[14] + e[15]);
            if (qn == 0) lsum0 += (s0 + s1) + (s2 + s3);
            else         lsum1 += (s0 + s1) + (s2 + s3);
#pragma unroll
            for (int f = 0; f < 2; ++f) {
                p[qn][f].u[0] = pk2bf(e[4 * f + 0], e[4 * f + 1]);
                p[qn][f].u[1] = pk2bf(e[4 * f + 2], e[4 * f + 3]);
                p[qn][f].u[2] = pk2bf(e[8 + 4 * f + 0], e[8 + 4 * f + 1]);
                p[qn][f].u[3] = pk2bf(e[8 + 4 * f + 2], e[8 + 4 * f + 3]);
            }
        }
#pragma unroll
        for (int dn = 0; dn < 3; ++dn) {
#pragma unroll
            for (int f = 0; f < 2; ++f) {
                bf16x8 vb = *reinterpret_cast<const bf16x8*>(
                    &Vf[kbase + ((dn * 2 + f) << 9) + voff]);
                acc[0][dn] = mfma32(p[0][f].v8, vb, acc[0][dn]);
                acc[1][dn] = mfma32(p[1][f].v8, vb, acc[1][dn]);
            }
        }
    }

    // ---- cross-wave reduce over wk (pairs, stride 36 floats) ----
    const int rbase = (wr * 64 + l) * 36;
#pragma unroll
    for (int ps = 0; ps < 3; ++ps) {
        __syncthreads();
        if (wk == 1) {
#pragma unroll
            for (int c = 0; c < 2; ++c) {
                int c2 = ps * 2 + c, qn = c2 / 3, dn = c2 % 3;
#pragma unroll
                for (int u = 0; u < 4; ++u) {
                    f32x4 tmp;
#pragma unroll
                    for (int j = 0; j < 4; ++j) tmp[j] = acc[qn][dn][u * 4 + j];
                    *reinterpret_cast<f32x4*>(&red[rbase + c * 16 + u * 4]) = tmp;
                }
            }
        }
        __syncthreads();
        if (wk == 0) {
#pragma unroll
            for (int c = 0; c < 2; ++c) {
                int c2 = ps * 2 + c, qn = c2 / 3, dn = c2 % 3;
#pragma unroll
                for (int u = 0; u < 4; ++u) {
                    f32x4 tmp = *reinterpret_cast<const f32x4*>(&red[rbase + c * 16 + u * 4]);
#pragma unroll
                    for (int j = 0; j < 4; ++j) acc[qn][dn][u * 4 + j] += tmp[j];
                }
            }
        }
    }

    // ---- softmax denominator: h-fold in-wave, wk-fold + transpose via LDS ----
    lsum0 += __shfl_xor(lsum0, 32);
    lsum1 += __shfl_xor(lsum1, 32);
    __syncthreads();                      // phase-3 reads above complete
    if (wk == 1 && h == 0) {
        red[(wr * 2 + 0) * 32 + l31] = lsum0;
        red[(wr * 2 + 1) * 32 + l31] = lsum1;
    }
    __syncthreads();
    if (wk == 0 && h == 0) {
        red[128 + (wr * 2 + 0) * 32 + l31] = 1.f / (lsum0 + red[(wr * 2 + 0) * 32 + l31]);
        red[128 + (wr * 2 + 1) * 32 + l31] = 1.f / (lsum1 + red[(wr * 2 + 1) * 32 + l31]);
    }
    __syncthreads();
    if (wk == 0) {
        const int b = bh >> 3, head = bh & 7;
#pragma unroll
        for (int qn = 0; qn < 2; ++qn) {
#pragma unroll
            for (int reg = 0; reg < 16; ++reg) {
                int qloc = (reg & 3) + 8 * (reg >> 2) + 4 * h;
                int n = q0 + wr * 64 + qn * 32 + qloc;
                float inv = red[128 + (wr * 2 + qn) * 32 + qloc];
                int rowoff = (b * 4096 + n) * 768 + head * 96;
#pragma unroll
                for (int dn = 0; dn < 3; ++dn)
                    Og[rowoff + dn * 32 + l31] = f2bf(acc[qn][dn][reg] * inv);
            }
        }
    }
}

// ---------------- proj GEMM: [8192x768] x [768x768]^T -> FP32 out ----------------
// R18: same 2-phase STAGE-ahead double buffer as qkv_gemm.
__global__ __launch_bounds__(256) void proj_gemm(const unsigned short* __restrict__ A,
                                                 const unsigned short* __restrict__ W,
                                                 float* __restrict__ out) {
    __shared__ __align__(16) unsigned short S[16384];  // dbuf: buf b at b*8192: A[0,4096) B[4096,8192)
    const int t = threadIdx.x;
    const int w = t >> 6, l = t & 63;
    const int wm = (w >> 1) * 64, wn = (w & 1) * 64;
    const int lr = l & 15, lq = l >> 4;
    const int m0 = blockIdx.y * 128, n0 = blockIdx.x * 128;
    f32x4 acc[4][4] = {};

#if GLL_LANE
#define PSTAGE(ks, boff)                                                        \
    {                                                                           \
        const int k0s = (ks) * 32;                                              \
        _Pragma("unroll")                                                       \
        for (int i = 0; i < 2; ++i) {                                           \
            int v = t + i * 256;                                                \
            int r = v >> 2, c8 = (v & 3) * 8;                                   \
            unsigned short* dst = &S[(boff) + (w * 64 + i * 256) * 8];          \
            gload16(&A[(m0 + r) * 768 + k0s + c8], dst);                        \
            gload16(&W[(n0 + r) * 768 + k0s + c8], dst + 4096);                 \
        }                                                                       \
    }
#else
#define PSTAGE(ks, boff)                                                        \
    {                                                                           \
        const int k0s = (ks) * 32;                                              \
        _Pragma("unroll")                                                       \
        for (int i = 0; i < 2; ++i) {                                           \
            int v = t + i * 256;                                                \
            int r = v >> 2, c8 = (v & 3) * 8;                                   \
            *reinterpret_cast<ushort8*>(&S[(boff) + v * 8]) =                   \
                *reinterpret_cast<const ushort8*>(&A[(m0 + r) * 768 + k0s + c8]);\
            *reinterpret_cast<ushort8*>(&S[(boff) + 4096 + v * 8]) =            \
                *reinterpret_cast<const ushort8*>(&W[(n0 + r) * 768 + k0s + c8]);\
        }                                                                       \
    }
#endif

    PSTAGE(0, 0);
    __syncthreads();
    for (int ks = 0; ks < 24; ++ks) {
        const int cur = (ks & 1) ? 8192 : 0;
        if (ks < 23) PSTAGE(ks + 1, 8192 - cur);
        bf16x8 af[4], bfr[4];
#pragma unroll
        for (int mt = 0; mt < 4; ++mt)
            af[mt] = *reinterpret_cast<const bf16x8*>(&S[cur + (wm + mt * 16 + lr) * 32 + lq * 8]);
#pragma unroll
        for (int nt = 0; nt < 4; ++nt)
            bfr[nt] = *reinterpret_cast<const bf16x8*>(&S[cur + 4096 + (wn + nt * 16 + lr) * 32 + lq * 8]);
#pragma unroll
        for (int mt = 0; mt < 4; ++mt)
#pragma unroll
            for (int nt = 0; nt < 4; ++nt)
                acc[mt][nt] = mfma16(af[mt], bfr[nt], acc[mt][nt]);
        __syncthreads();
    }
#undef PSTAGE
#pragma unroll
    for (int nt = 0; nt < 4; ++nt) {
        int gn = n0 + wn + nt * 16 + lr;
#pragma unroll
        for (int mt = 0; mt < 4; ++mt) {
#pragma unroll
            for (int r = 0; r < 4; ++r) {
                int gm = m0 + wm + mt * 16 + lq * 4 + r;
                out[gm * 768 + gn] = acc[mt][nt][r];
            }
        }
    }
}

extern "C" void kernel_launch(void* const* d_in, const int* in_sizes, int n_in,
                              void* d_out, int out_size, void* d_ws, size_t ws_size,
                              hipStream_t stream) {
    const float* x     = (const float*)d_in[0];   // [2,4096,768] fp32
    const float* wqkv  = (const float*)d_in[1];   // [2304,768] fp32
    const float* wproj = (const float*)d_in[2];   // [768,768] fp32
    float* out = (float*)d_out;                   // fp32 [2,4096,768]
    char* ws = (char*)d_ws;
    unsigned short* xb     = (unsigned short*)(ws);             // 12582912
    unsigned short* wqkvb  = (unsigned short*)(ws + 12582912);  // 3538944
    unsigned short* wprojb = (unsigned short*)(ws + 16121856);  // 1179648
    unsigned short* Qf     = (unsigned short*)(ws + 17301504);  // frag chunks
    unsigned short* Kf     = (unsigned short*)(ws + 29884416);  // frag chunks
    unsigned short* Vf     = (unsigned short*)(ws + 42467328);  // frag chunks
    unsigned short* attnb  = xb;                                // reuse: [B,N,C] bf16

    cvt3_f32_bf16<<<8448, 256, 0, stream>>>(x, wqkv, wproj, xb, wqkvb, wprojb);
    qkv_gemm<<<dim3(18, 64), 256, 0, stream>>>(xb, wqkvb, Qf, Kf, Vf);
    attn_kernel<<<512, 256, 0, stream>>>(Qf, Kf, Vf, attnb);
    proj_gemm<<<dim3(6, 64), 256, 0, stream>>>(attnb, wprojb, out);
}